// Round 1
// baseline (1671.649 us; speedup 1.0000x reference)
//
#include <hip/hip_runtime.h>
#include <hip/hip_bf16.h>

#define S_ 64
#define B_ 32
#define H_ 1024
#define E_ 512
#define V_ 32000

typedef unsigned short ushort_t;
typedef __attribute__((ext_vector_type(8))) short short8;
typedef __attribute__((ext_vector_type(4))) float f32x4;

__device__ __forceinline__ ushort_t f32_bf16(float x) {
    union { float f; unsigned u; } v; v.f = x;
    unsigned r = v.u + 0x7FFF + ((v.u >> 16) & 1);   // RNE
    return (ushort_t)(r >> 16);
}

__device__ __forceinline__ float bf16_f32(ushort_t x) {
    union { unsigned u; float f; } v; v.u = ((unsigned)x) << 16;
    return v.f;
}

// ---------------- fp32 -> bf16 convert (vectorized, grid-stride) --------------
__global__ void cvt_bf16(const float* __restrict__ src, ushort_t* __restrict__ dst, int n4) {
    int i = blockIdx.x * blockDim.x + threadIdx.x;
    int stride = gridDim.x * blockDim.x;
    const float4* s4 = (const float4*)src;
    ushort4* d4 = (ushort4*)dst;
    for (; i < n4; i += stride) {
        float4 v = s4[i];
        ushort4 o;
        o.x = f32_bf16(v.x); o.y = f32_bf16(v.y);
        o.z = f32_bf16(v.z); o.w = f32_bf16(v.w);
        d4[i] = o;
    }
}

// ---------------- init hidden: fp32 [2,B,H] -> bf16 double-buffers (slot 1) ---
__global__ void init_hidden(const float* __restrict__ hid,
                            ushort_t* __restrict__ h0buf, ushort_t* __restrict__ h1buf) {
    int i = blockIdx.x * blockDim.x + threadIdx.x;  // 0 .. 2*B*H-1
    int j = i & (B_ * H_ - 1);
    if (i < B_ * H_) h0buf[B_ * H_ + j] = f32_bf16(hid[i]);
    else             h1buf[B_ * H_ + j] = f32_bf16(hid[i]);
}

// ---------------- embedding gather -> bf16 X [S*B, E] -------------------------
__global__ void gather_emb(const int* __restrict__ tok, const float* __restrict__ emb,
                           ushort_t* __restrict__ xb) {
    int m = blockIdx.x;                  // 0..S*B-1
    int t = tok[m];
    const float4* src = (const float4*)(emb + (long)t * E_);
    ushort4* dst = (ushort4*)(xb + (long)m * E_);
    int i = threadIdx.x;                 // blockDim = 128 = E/4
    float4 v = src[i];
    ushort4 o;
    o.x = f32_bf16(v.x); o.y = f32_bf16(v.y);
    o.z = f32_bf16(v.z); o.w = f32_bf16(v.w);
    dst[i] = o;
}

// ---------------- xproj = X @ Wx0^T + bh0  (fp32 out, [S*B, H]) ---------------
// one 16x16 C-tile per wave, direct global loads of fragments
__global__ __launch_bounds__(256) void xproj_kernel(const ushort_t* __restrict__ Xb,
                                                    const ushort_t* __restrict__ Wx0b,
                                                    const float* __restrict__ bh0,
                                                    float* __restrict__ xproj) {
    int wid = (blockIdx.x * 256 + threadIdx.x) >> 6;  // 0..8191
    int lane = threadIdx.x & 63;
    int quad = lane >> 4;
    int nt = wid & 63, mt = wid >> 6;                 // mt 0..127, nt 0..63
    int mrow = mt * 16 + (lane & 15);
    int nrow = nt * 16 + (lane & 15);
    const short8* Ap = (const short8*)(Xb + (long)mrow * E_ + quad * 8);
    const short8* Bp = (const short8*)(Wx0b + (long)nrow * E_ + quad * 8);
    f32x4 acc = {0.f, 0.f, 0.f, 0.f};
#pragma unroll
    for (int k = 0; k < E_ / 32; ++k)
        acc = __builtin_amdgcn_mfma_f32_16x16x32_bf16(Ap[k * 4], Bp[k * 4], acc, 0, 0, 0);
    float bias = bh0[nrow];
#pragma unroll
    for (int r = 0; r < 4; ++r) {
        int m = mt * 16 + quad * 4 + r;
        xproj[(long)m * H_ + nrow] = acc[r] + bias;
    }
}

// ---------------- one pipeline phase: layer0(t=p) + layer1(t=p-1) -------------
// h0buf/h1buf: [2][B*H] bf16 double buffers.  tops: [S*B, H] bf16.
__global__ __launch_bounds__(256) void step_kernel(const ushort_t* __restrict__ Wh0b,
                                                   const ushort_t* __restrict__ Wx1b,
                                                   const ushort_t* __restrict__ Wh1b,
                                                   const float* __restrict__ bh1,
                                                   const float* __restrict__ xproj,
                                                   ushort_t* __restrict__ h0buf,
                                                   ushort_t* __restrict__ h1buf,
                                                   ushort_t* __restrict__ tops,
                                                   int p) {
    int lb = blockIdx.x;           // 0..63
    int lane = threadIdx.x & 63;
    int widx = threadIdx.x >> 6;
    int quad = lane >> 4;
    if (lb < 32) {
        // ---- layer 0, step t=p: h0[p] = tanh(xproj[p] + h0[p-1] @ Wh0^T)
        if (p >= S_) return;
        int wid = lb * 4 + widx;                 // 0..127
        int nt = wid & 63, mt = wid >> 6;
        int b0 = mt * 16 + (lane & 15);
        int h = nt * 16 + (lane & 15);
        const ushort_t* Aprev = h0buf + ((p + 1) & 1) * (B_ * H_);
        const short8* Ap = (const short8*)(Aprev + (long)b0 * H_ + quad * 8);
        const short8* Wp = (const short8*)(Wh0b + (long)h * H_ + quad * 8);
        f32x4 acc = {0.f, 0.f, 0.f, 0.f};
#pragma unroll
        for (int k = 0; k < H_ / 32; ++k)
            acc = __builtin_amdgcn_mfma_f32_16x16x32_bf16(Ap[k * 4], Wp[k * 4], acc, 0, 0, 0);
        ushort_t* out = h0buf + (p & 1) * (B_ * H_);
        const float* xp = xproj + (long)p * B_ * H_;
#pragma unroll
        for (int r = 0; r < 4; ++r) {
            int b = mt * 16 + quad * 4 + r;
            float v = tanhf(acc[r] + xp[b * H_ + h]);
            out[b * H_ + h] = f32_bf16(v);
        }
    } else {
        // ---- layer 1, step t=p-1: h1[t] = tanh(h0[t]@Wx1^T + h1[t-1]@Wh1^T + bh1)
        if (p < 1) return;
        int t = p - 1;
        int wid = (lb - 32) * 4 + widx;
        int nt = wid & 63, mt = wid >> 6;
        int b0 = mt * 16 + (lane & 15);
        int h = nt * 16 + (lane & 15);
        const ushort_t* A0 = h0buf + (t & 1) * (B_ * H_);        // h0[t]
        const ushort_t* A1 = h1buf + ((t + 1) & 1) * (B_ * H_);  // h1[t-1]
        const short8* Ap0 = (const short8*)(A0 + (long)b0 * H_ + quad * 8);
        const short8* Wp0 = (const short8*)(Wx1b + (long)h * H_ + quad * 8);
        const short8* Ap1 = (const short8*)(A1 + (long)b0 * H_ + quad * 8);
        const short8* Wp1 = (const short8*)(Wh1b + (long)h * H_ + quad * 8);
        f32x4 acc = {0.f, 0.f, 0.f, 0.f};
#pragma unroll
        for (int k = 0; k < H_ / 32; ++k)
            acc = __builtin_amdgcn_mfma_f32_16x16x32_bf16(Ap0[k * 4], Wp0[k * 4], acc, 0, 0, 0);
#pragma unroll
        for (int k = 0; k < H_ / 32; ++k)
            acc = __builtin_amdgcn_mfma_f32_16x16x32_bf16(Ap1[k * 4], Wp1[k * 4], acc, 0, 0, 0);
        float bias = bh1[h];
        ushort_t* out = h1buf + (t & 1) * (B_ * H_);
        ushort_t* top = tops + (long)t * B_ * H_;
#pragma unroll
        for (int r = 0; r < 4; ++r) {
            int b = mt * 16 + quad * 4 + r;
            float v = tanhf(acc[r] + bias);
            ushort_t bv = f32_bf16(v);
            out[b * H_ + h] = bv;
            top[b * H_ + h] = bv;
        }
    }
}

// ---------------- final GEMM: logits = tops @ Wout^T + bout -------------------
// m97-style: 128x128 block tile, BK=32, 4 waves each computing 64x64 (4x4 frags)
#define BM 128
#define BN 128
#define BK 32

__device__ __forceinline__ void ld_lds16(const ushort_t* g, ushort_t* l) {
    __builtin_amdgcn_global_load_lds((const __attribute__((address_space(1))) void*)g,
                                     (__attribute__((address_space(3))) void*)l, 16, 0, 0);
}

__global__ __launch_bounds__(256) void out_gemm(const ushort_t* __restrict__ A,   // [2048,1024]
                                                const ushort_t* __restrict__ Bw,  // [32000,1024]
                                                const float* __restrict__ bout,
                                                float* __restrict__ C) {
    __shared__ __align__(16) ushort_t lA[BM * BK];  // 8KB
    __shared__ __align__(16) ushort_t lB[BN * BK];  // 8KB
    int mblk = blockIdx.x;   // 0..15
    int nblk = blockIdx.y;   // 0..249
    int tid = threadIdx.x;
    int lane = tid & 63;
    int w = tid >> 6;
    int quad = lane >> 4;
    // staging map: thread tid, round r covers (row = r*64 + tid/4, k = (tid%4)*8)
    int srow = tid >> 2;
    int skol = (tid & 3) * 8;
    const ushort_t* Ag = A + (long)(mblk * BM + srow) * H_ + skol;
    const ushort_t* Bg = Bw + (long)(nblk * BN + srow) * H_ + skol;
    ushort_t* lA0 = lA + tid * 8;
    ushort_t* lA1 = lA + 2048 + tid * 8;
    ushort_t* lB0 = lB + tid * 8;
    ushort_t* lB1 = lB + 2048 + tid * 8;

    int msub = (w & 1) * 64;
    int nsub = (w >> 1) * 64;
    f32x4 acc[4][4];
#pragma unroll
    for (int i = 0; i < 4; ++i)
#pragma unroll
        for (int j = 0; j < 4; ++j) acc[i][j] = (f32x4){0.f, 0.f, 0.f, 0.f};

    for (int k0 = 0; k0 < H_; k0 += BK) {
        ld_lds16(Ag + k0, lA0);
        ld_lds16(Ag + 64 * H_ + k0, lA1);
        ld_lds16(Bg + k0, lB0);
        ld_lds16(Bg + 64 * H_ + k0, lB1);
        __syncthreads();
        short8 af[4], bf[4];
#pragma unroll
        for (int i = 0; i < 4; ++i)
            af[i] = *(const short8*)&lA[(msub + i * 16 + (lane & 15)) * BK + quad * 8];
#pragma unroll
        for (int j = 0; j < 4; ++j)
            bf[j] = *(const short8*)&lB[(nsub + j * 16 + (lane & 15)) * BK + quad * 8];
#pragma unroll
        for (int i = 0; i < 4; ++i)
#pragma unroll
            for (int j = 0; j < 4; ++j)
                acc[i][j] = __builtin_amdgcn_mfma_f32_16x16x32_bf16(af[i], bf[j], acc[i][j], 0, 0, 0);
        __syncthreads();
    }

#pragma unroll
    for (int j = 0; j < 4; ++j) {
        int n = nblk * BN + nsub + j * 16 + (lane & 15);
        float bo = bout[n];
#pragma unroll
        for (int i = 0; i < 4; ++i) {
#pragma unroll
            for (int r = 0; r < 4; ++r) {
                int m = mblk * BM + msub + i * 16 + quad * 4 + r;
                C[(long)m * V_ + n] = acc[i][j][r] + bo;
            }
        }
    }
}

// ---------------- final hidden: bf16 slot-1 buffers -> fp32 tail of d_out -----
__global__ void final_hidden(const ushort_t* __restrict__ h0buf,
                             const ushort_t* __restrict__ h1buf,
                             float* __restrict__ out) {
    int i = blockIdx.x * blockDim.x + threadIdx.x;  // 0 .. 2*B*H-1
    int j = i & (B_ * H_ - 1);
    // h0[63] lives in h0buf slot (63&1)=1 ; h1[63] in h1buf slot 1
    ushort_t v = (i < B_ * H_) ? h0buf[B_ * H_ + j] : h1buf[B_ * H_ + j];
    out[(long)S_ * B_ * V_ + i] = bf16_f32(v);
}

extern "C" void kernel_launch(void* const* d_in, const int* in_sizes, int n_in,
                              void* d_out, int out_size, void* d_ws, size_t ws_size,
                              hipStream_t stream) {
    const int*   tok  = (const int*)d_in[0];
    const float* hid  = (const float*)d_in[1];
    const float* emb  = (const float*)d_in[2];
    const float* Wx0  = (const float*)d_in[3];
    const float* Wh0  = (const float*)d_in[4];
    const float* bh0  = (const float*)d_in[5];
    const float* Wx1  = (const float*)d_in[6];
    const float* Wh1  = (const float*)d_in[7];
    const float* bh1  = (const float*)d_in[8];
    const float* Wout = (const float*)d_in[9];
    const float* bout = (const float*)d_in[10];
    float* out = (float*)d_out;

    char* ws = (char*)d_ws;
    size_t off = 0;
    ushort_t* woutb = (ushort_t*)(ws + off); off += (size_t)V_ * H_ * 2;       // 65,536,000
    ushort_t* wh0b  = (ushort_t*)(ws + off); off += (size_t)H_ * H_ * 2;       // 2MB
    ushort_t* wx1b  = (ushort_t*)(ws + off); off += (size_t)H_ * H_ * 2;
    ushort_t* wh1b  = (ushort_t*)(ws + off); off += (size_t)H_ * H_ * 2;
    ushort_t* wx0b  = (ushort_t*)(ws + off); off += (size_t)H_ * E_ * 2;       // 1MB
    ushort_t* xb    = (ushort_t*)(ws + off); off += (size_t)S_ * B_ * E_ * 2;  // 2MB
    float*    xproj = (float*)(ws + off);    off += (size_t)S_ * B_ * H_ * 4;  // 8MB
    ushort_t* topsb = (ushort_t*)(ws + off); off += (size_t)S_ * B_ * H_ * 2;  // 4MB
    ushort_t* h0b   = (ushort_t*)(ws + off); off += (size_t)2 * B_ * H_ * 2;
    ushort_t* h1b   = (ushort_t*)(ws + off); off += (size_t)2 * B_ * H_ * 2;

    // weight conversions (independent, back-to-back on stream)
    cvt_bf16<<<2048, 256, 0, stream>>>(Wout, woutb, V_ * H_ / 4);
    cvt_bf16<<<256, 256, 0, stream>>>(Wh0, wh0b, H_ * H_ / 4);
    cvt_bf16<<<256, 256, 0, stream>>>(Wx1, wx1b, H_ * H_ / 4);
    cvt_bf16<<<256, 256, 0, stream>>>(Wh1, wh1b, H_ * H_ / 4);
    cvt_bf16<<<128, 256, 0, stream>>>(Wx0, wx0b, H_ * E_ / 4);
    init_hidden<<<256, 256, 0, stream>>>(hid, h0b, h1b);
    gather_emb<<<S_ * B_, 128, 0, stream>>>(tok, emb, xb);
    // x-side projection for all timesteps, one GEMM
    xproj_kernel<<<2048, 256, 0, stream>>>(xb, wx0b, bh0, xproj);
    // pipelined recurrence: phase p = layer0(t=p) || layer1(t=p-1)
    for (int p = 0; p <= S_; ++p)
        step_kernel<<<64, 256, 0, stream>>>(wh0b, wx1b, wh1b, bh1, xproj, h0b, h1b, topsb, p);
    // output projection
    out_gemm<<<dim3(16, 250), 256, 0, stream>>>(topsb, woutb, bout, out);
    final_hidden<<<256, 256, 0, stream>>>(h0b, h1b, out);
}